// Round 6
// baseline (28.541 us; speedup 1.0000x reference)
//
#include <hip/hip_runtime.h>

#define C 32
#define H 192
#define W 192
#define HW (H*W)        // 36864
#define NPIX (HW*2)     // 73728
#define KK 7
#define TAPS 49

// ---------------- K1: z[hw][o*2+n] = sum_c cw[o,c]*x[c][hw][n] ----------------
// 1152 blocks = 8 XCD chunks of 144 = (18 hw-blocks x 8 o-passes).
// XCD n covers pixel rows [24n, 24n+24) -- matches k2's band for L2 handoff.
__global__ __launch_bounds__(256) void k1_mix(
    const float* __restrict__ x, const float* __restrict__ cw, float* __restrict__ z)
{
    __shared__ float wl[128];                    // [c][oo] = cw[ob+oo][c]
    const int b  = blockIdx.x;
    const int l  = (b & 7) * 144 + (b >> 3);     // bijective (1152%8==0)
    const int hwblk = l >> 3;                    // 0..143
    const int ob    = (l & 7) * 4;               // 8 o-passes of 4
    const int tid   = threadIdx.x;

    if (tid < 128) wl[tid] = cw[(ob + (tid & 3)) * C + (tid >> 2)];
    __syncthreads();

    const int hw = hwblk * 256 + tid;
    const float2* x2 = reinterpret_cast<const float2*>(x);
    float2 xv[C];
#pragma unroll
    for (int c = 0; c < C; ++c) xv[c] = x2[(size_t)c * HW + hw];

    float acc[4][2];
#pragma unroll
    for (int oo = 0; oo < 4; ++oo) { acc[oo][0] = 0.f; acc[oo][1] = 0.f; }

#pragma unroll
    for (int c = 0; c < C; ++c) {
        const float4 wt = *reinterpret_cast<const float4*>(&wl[c * 4]);  // uniform broadcast
        acc[0][0] += wt.x * xv[c].x;  acc[0][1] += wt.x * xv[c].y;
        acc[1][0] += wt.y * xv[c].x;  acc[1][1] += wt.y * xv[c].y;
        acc[2][0] += wt.z * xv[c].x;  acc[2][1] += wt.z * xv[c].y;
        acc[3][0] += wt.w * xv[c].x;  acc[3][1] += wt.w * xv[c].y;
    }

    float* zp = z + (size_t)hw * 64 + ob * 2;    // 8 contiguous floats
    *reinterpret_cast<float4*>(zp)     = make_float4(acc[0][0], acc[0][1], acc[1][0], acc[1][1]);
    *reinterpret_cast<float4*>(zp + 4) = make_float4(acc[2][0], acc[2][1], acc[3][0], acc[3][1]);
}

// ---------------- K2: pixelwise 7x7 over transposed z ----------------
// Block = 256 thr (4 waves); wave = 8 output px of row h, lane = o*2+n.
// LDS weights (uniform ds_read_b128 broadcast). ALL 7 z-rows prefetched to
// registers (98 VGPRs) before any FMA -> one latency exposure per wave.
#define K2_BLOCKS 1152   // 192 rows x 6 wq
__global__ __launch_bounds__(256, 3) void k2_conv(
    const float* __restrict__ z, const float* __restrict__ w1,
    const float* __restrict__ cb, float* __restrict__ out)
{
    __shared__ float wl[TAPS * 32];              // 6.27 KB
    __shared__ float tr[4][8 * 66];              // 8.45 KB

    const int b  = blockIdx.x;
    const int l  = (b & 7) * (K2_BLOCKS / 8) + (b >> 3);  // XCD row bands (24 rows each)
    const int h  = l / 6;
    const int wq = l % 6;
    const int tid  = threadIdx.x;
    const int wv   = __builtin_amdgcn_readfirstlane(tid >> 6);  // uniform in SGPR
    const int lane = tid & 63;                   // o*2+n
    const int w0   = wq * 32 + wv * 8;

    // stage w1[t][h][wq*32 .. +32) for all 49 taps
#pragma unroll
    for (int k = 0; k < 7; ++k) {
        const int v = k * 256 + tid;
        if (v < TAPS * 32) {
            const int t = v >> 5, c = v & 31;
            wl[v] = w1[(size_t)t * HW + h * W + wq * 32 + c];
        }
    }
    __syncthreads();

    // ---- prefetch ALL 7 z-rows (14 cols each) into registers ----
    float zb[KK][14];
    const bool wedge = (w0 == 0) || (w0 == W - 8);             // scalar branch (wv uniform)
    if (!wedge) {
#pragma unroll
        for (int i = 0; i < KK; ++i) {
            const int yy = h + i - 3;
            if (yy >= 0 && yy < H) {                           // uniform
                const float* p = z + ((size_t)yy * W + (w0 - 3)) * 64 + lane;
#pragma unroll
                for (int k = 0; k < 14; ++k) zb[i][k] = p[k * 64];
            } else {
#pragma unroll
                for (int k = 0; k < 14; ++k) zb[i][k] = 0.f;
            }
        }
    } else {
#pragma unroll
        for (int i = 0; i < KK; ++i) {
            const int yy = h + i - 3;
            if (yy >= 0 && yy < H) {
                const float* p = z + (size_t)yy * (W * 64) + lane;
#pragma unroll
                for (int k = 0; k < 14; ++k) {
                    const int cc  = w0 - 3 + k;                // uniform
                    const int ccl = cc < 0 ? 0 : (cc > W - 1 ? W - 1 : cc);
                    const float v = p[ccl * 64];
                    zb[i][k] = (cc == ccl) ? v : 0.f;
                }
            } else {
#pragma unroll
                for (int k = 0; k < 14; ++k) zb[i][k] = 0.f;
            }
        }
    }

    // ---- 49-tap accumulate, weights via LDS broadcast ----
    float acc[8];
#pragma unroll
    for (int p = 0; p < 8; ++p) acc[p] = 0.f;

#pragma unroll
    for (int i = 0; i < KK; ++i) {
#pragma unroll
        for (int j = 0; j < KK; ++j) {
            const float4 wa  = *reinterpret_cast<const float4*>(&wl[(i*KK + j) * 32 + wv * 8]);
            const float4 wb4 = *reinterpret_cast<const float4*>(&wl[(i*KK + j) * 32 + wv * 8 + 4]);
            acc[0] += wa.x  * zb[i][j + 0];
            acc[1] += wa.y  * zb[i][j + 1];
            acc[2] += wa.z  * zb[i][j + 2];
            acc[3] += wa.w  * zb[i][j + 3];
            acc[4] += wb4.x * zb[i][j + 4];
            acc[5] += wb4.y * zb[i][j + 5];
            acc[6] += wb4.z * zb[i][j + 6];
            acc[7] += wb4.w * zb[i][j + 7];
        }
    }

    // epilogue: bias + per-wave LDS transpose -> 16B stores
    const float bias = cb[lane >> 1];
    float* trw = &tr[wv][0];
#pragma unroll
    for (int p = 0; p < 8; ++p) trw[p * 66 + lane] = acc[p] + bias;
    __syncthreads();

    const int o = lane >> 1, half = lane & 1;
    float v8[8];
#pragma unroll
    for (int m = 0; m < 8; ++m) {
        const int f = half * 8 + m;
        v8[m] = trw[(f >> 1) * 66 + o * 2 + (f & 1)];
    }
    float* obase = out + (size_t)o * NPIX + ((size_t)h * W + w0) * 2 + half * 8;
    *reinterpret_cast<float4*>(obase)     = make_float4(v8[0], v8[1], v8[2], v8[3]);
    *reinterpret_cast<float4*>(obase + 4) = make_float4(v8[4], v8[5], v8[6], v8[7]);
}

extern "C" void kernel_launch(void* const* d_in, const int* in_sizes, int n_in,
                              void* d_out, int out_size, void* d_ws, size_t ws_size,
                              hipStream_t stream) {
    const float* x  = (const float*)d_in[0];   // (C,H,W,2)
    const float* w1 = (const float*)d_in[1];   // (1,1,49,H,W)
    const float* cw = (const float*)d_in[2];   // (C_out, C_in)
    const float* cb = (const float*)d_in[3];   // (C,)
    float* z   = (float*)d_ws;                 // (HW, 64) transposed mix
    float* out = (float*)d_out;                // (C,H,W,2)

    hipLaunchKernelGGL(k1_mix, dim3(1152), dim3(256), 0, stream, x, cw, z);
    hipLaunchKernelGGL(k2_conv, dim3(K2_BLOCKS), dim3(256), 0, stream, z, w1, cb, out);
}

// Round 7
// 23.890 us; speedup vs baseline: 1.1947x; 1.1947x over previous
//
#include <hip/hip_runtime.h>

#define C 32
#define H 192
#define W 192
#define HW (H*W)        // 36864
#define NPIX (HW*2)     // 73728
#define KK 7

// ---------------- K1 (exact R4): z[hw][o*2+n] = sum_c cw[o,c]*x[c][hw][n] ----------------
__global__ __launch_bounds__(256) void k1_mix(
    const float* __restrict__ x, const float* __restrict__ cw, float* __restrict__ z)
{
    __shared__ float wl[256];
    const int b  = blockIdx.x;
    const int l  = (b & 7) * 72 + (b >> 3);      // bijective XCD swizzle (576%8==0)
    const int hwblk = l >> 2;
    const int ob    = (l & 3) * 8;
    const int tid   = threadIdx.x;

    wl[tid] = cw[(ob + (tid & 7)) * C + (tid >> 3)];   // wl[c*8+oo]
    __syncthreads();

    const int hw = hwblk * 256 + tid;
    const float2* x2 = reinterpret_cast<const float2*>(x);
    float2 xv[C];
#pragma unroll
    for (int c = 0; c < C; ++c) xv[c] = x2[(size_t)c * HW + hw];

    float acc[8][2];
#pragma unroll
    for (int oo = 0; oo < 8; ++oo) { acc[oo][0] = 0.f; acc[oo][1] = 0.f; }

#pragma unroll
    for (int c = 0; c < C; ++c) {
        const float4 wa = *reinterpret_cast<const float4*>(&wl[c * 8]);
        const float4 wb = *reinterpret_cast<const float4*>(&wl[c * 8 + 4]);
        const float wt[8] = { wa.x, wa.y, wa.z, wa.w, wb.x, wb.y, wb.z, wb.w };
#pragma unroll
        for (int oo = 0; oo < 8; ++oo) {
            acc[oo][0] += wt[oo] * xv[c].x;
            acc[oo][1] += wt[oo] * xv[c].y;
        }
    }

    float* zp = z + (size_t)hw * 64 + ob * 2;
#pragma unroll
    for (int q = 0; q < 4; ++q) {
        float4 r = make_float4(acc[2*q][0], acc[2*q][1], acc[2*q+1][0], acc[2*q+1][1]);
        *reinterpret_cast<float4*>(zp + 4 * q) = r;
    }
}

// ---------------- K2: R4 structure, weights via SCALAR loads (no weight LDS) ----------------
// Block = 256 thr (4 waves); wave = 8 output px of row h, lane = o*2+n.
// All weight addresses are wave-uniform (h,wq from blockIdx; wv readfirstlane'd)
// -> compiler scalarizes to s_load, weights consumed as SGPR operands of v_fmac.
#define K2_BLOCKS 1152   // 192 rows x 6 wq
__global__ __launch_bounds__(256) void k2_conv(
    const float* __restrict__ z, const float* __restrict__ w1,
    const float* __restrict__ cb, float* __restrict__ out)
{
    __shared__ float tr[4][8 * 66];              // epilogue transpose only

    const int b  = blockIdx.x;
    const int l  = (b & 7) * (K2_BLOCKS / 8) + (b >> 3);  // XCD row bands (24 rows each)
    const int h  = l / 6;
    const int wq = l % 6;
    const int tid  = threadIdx.x;
    const int wv   = __builtin_amdgcn_readfirstlane(tid >> 6);  // uniform in SGPR
    const int lane = tid & 63;                   // o*2+n
    const int w0   = wq * 32 + wv * 8;

    float acc[8];
#pragma unroll
    for (int p = 0; p < 8; ++p) acc[p] = 0.f;

    const bool wedge = (w0 == 0) || (w0 == W - 8);   // scalar branch (w0 uniform)

#pragma unroll
    for (int i = 0; i < KK; ++i) {
        const int yy = h + i - 3;
        if (yy < 0 || yy >= H) continue;         // uniform per block

        // z window cols w0-3 .. w0+10 (14), coalesced 256B per column load
        float zw[14];
        if (!wedge) {
            const float* p = z + ((size_t)yy * W + (w0 - 3)) * 64 + lane;
#pragma unroll
            for (int k = 0; k < 14; ++k) zw[k] = p[k * 64];
        } else {
            const float* p = z + (size_t)yy * (W * 64) + lane;
#pragma unroll
            for (int k = 0; k < 14; ++k) {
                const int cc  = w0 - 3 + k;                    // uniform
                const int ccl = cc < 0 ? 0 : (cc > W - 1 ? W - 1 : cc);
                const float v = p[ccl * 64];
                zw[k] = (cc == ccl) ? v : 0.f;
            }
        }

        // weights: wave-uniform addresses -> scalar pipe (s_load_dwordx8 per tap)
        const float* wp = w1 + (size_t)i * KK * HW + (size_t)h * W + w0;
#pragma unroll
        for (int j = 0; j < KK; ++j) {
#pragma unroll
            for (int px = 0; px < 8; ++px)
                acc[px] += wp[(size_t)j * HW + px] * zw[j + px];
        }
    }

    // epilogue: bias + per-wave LDS transpose -> 16B stores (exact R4)
    const float bias = cb[lane >> 1];
    float* trw = &tr[wv][0];
#pragma unroll
    for (int p = 0; p < 8; ++p) trw[p * 66 + lane] = acc[p] + bias;
    __syncthreads();

    const int o = lane >> 1, half = lane & 1;
    float v8[8];
#pragma unroll
    for (int m = 0; m < 8; ++m) {
        const int f = half * 8 + m;
        v8[m] = trw[(f >> 1) * 66 + o * 2 + (f & 1)];
    }
    float* obase = out + (size_t)o * NPIX + ((size_t)h * W + w0) * 2 + half * 8;
    *reinterpret_cast<float4*>(obase)     = make_float4(v8[0], v8[1], v8[2], v8[3]);
    *reinterpret_cast<float4*>(obase + 4) = make_float4(v8[4], v8[5], v8[6], v8[7]);
}

extern "C" void kernel_launch(void* const* d_in, const int* in_sizes, int n_in,
                              void* d_out, int out_size, void* d_ws, size_t ws_size,
                              hipStream_t stream) {
    const float* x  = (const float*)d_in[0];   // (C,H,W,2)
    const float* w1 = (const float*)d_in[1];   // (1,1,49,H,W)
    const float* cw = (const float*)d_in[2];   // (C_out, C_in)
    const float* cb = (const float*)d_in[3];   // (C,)
    float* z   = (float*)d_ws;                 // (HW, 64) transposed mix
    float* out = (float*)d_out;                // (C,H,W,2)

    hipLaunchKernelGGL(k1_mix, dim3(576), dim3(256), 0, stream, x, cw, z);
    hipLaunchKernelGGL(k2_conv, dim3(K2_BLOCKS), dim3(256), 0, stream, z, w1, cb, out);
}